// Round 4
// baseline (190.294 us; speedup 1.0000x reference)
//
#include <hip/hip_runtime.h>
#include <hip/hip_bf16.h>
#include <cstddef>
#include <cstdint>

#define SNL_N 50000
#define SNL_K 32
#define SNL_D 128
#define SNL_EPS 1e-12f
#define SNL_NBLOCKS 6250
#define SNL_REPS 2

// One wave per row. Anchor rows staged via global_load_lds (async, zero
// payload VGPRs): instruction t gathers anchors {2t, 2t+1} -- lane supplies
// a per-lane global address (chunk c32 of anchor 2t+h), HW deposits at
// wave-uniform LDS base + lane*16. 16 instrs in flight = 128 lines/wave.
// Rounds 2-3 showed the compiler serializes register-based gathers ~2-3
// deep (VGPR stayed 56-60); this sidesteps the register allocator.
__global__ __launch_bounds__(256) void snl_main(const float* __restrict__ emb,
                                                const float* __restrict__ psim,
                                                const int* __restrict__ aidx,
                                                float* __restrict__ out,
                                                float* __restrict__ part) {
    const int tid  = threadIdx.x;
    const int wid  = tid >> 6;       // wave in block
    const int lane = tid & 63;
    const int dc   = lane & 7;       // compute: 16B chunk within octet pass
    const int asub = lane >> 3;      // compute: anchor-in-octet
    const int c32  = lane & 31;      // staging: chunk of the anchor row
    const int h    = lane >> 5;      // staging: which anchor of the pair

    __shared__ float lds[4][4096];   // 16 KB per wave: 32 anchors x 512 B

    const float4* emb4 = reinterpret_cast<const float4*>(emb);
    float* wavebuf = &lds[wid][0];
    const float4* ldsw4 = reinterpret_cast<const float4*>(wavebuf);

    float loss_acc = 0.0f;

#pragma unroll 1
    for (int rep = 0; rep < SNL_REPS; ++rep) {
        const int i = (blockIdx.x * SNL_REPS + rep) * 4 + wid;

        // all 32 anchor ids (each half of the wave holds a full copy)
        const int av = aidx[(size_t)i * SNL_K + c32];

        // yi in registers (one 128B line per load, broadcast across octets)
        float4 yir[4];
#pragma unroll
        for (int it = 0; it < 4; ++it)
            yir[it] = emb4[(size_t)i * 32 + dc + it * 8];

        // spread anchor ids BEFORE the load burst so issue is back-to-back
        int aa[16];
#pragma unroll
        for (int t = 0; t < 16; ++t)
            aa[t] = __shfl(av, 2 * t + h, 64);

        // stage all 32 anchor rows: 16 async gather instrs, no payload VGPRs
#pragma unroll
        for (int t = 0; t < 16; ++t) {
            const float* gp = emb + (size_t)aa[t] * SNL_D + c32 * 4;
            float* lp = wavebuf + t * 256;   // 1024 B per instr
            __builtin_amdgcn_global_load_lds(
                (const __attribute__((address_space(1))) void*)gp,
                (__attribute__((address_space(3))) void*)lp,
                16, 0, 0);
        }

        __builtin_amdgcn_s_waitcnt(0x0F70);   // vmcnt(0); lgkm/exp don't-care

        float d2g[4];
#pragma unroll
        for (int g = 0; g < 4; ++g) {
            float acc = 0.0f;
#pragma unroll
            for (int it = 0; it < 4; ++it) {
                // anchor (g*8+asub), chunk (dc+8it): 8-lane phases hit 8
                // distinct bank-quads -> conflict-free ds_read_b128
                const float4 v = ldsw4[(size_t)(g * 8 + asub) * 32 + dc + it * 8];
                float dx = yir[it].x - v.x;
                float dy = yir[it].y - v.y;
                float dz = yir[it].z - v.z;
                float dw = yir[it].w - v.w;
                acc = fmaf(dx, dx, acc);
                acc = fmaf(dy, dy, acc);
                acc = fmaf(dz, dz, acc);
                acc = fmaf(dw, dw, acc);
            }
            acc += __shfl_xor(acc, 1, 64);
            acc += __shfl_xor(acc, 2, 64);
            acc += __shfl_xor(acc, 4, 64);
            d2g[g] = acc;
        }

        // transpose: lane k (and mirror k+32) gets d2 of anchor k
        const int src = (lane & 7) * 8;
        float t0 = __shfl(d2g[0], src, 64);
        float t1 = __shfl(d2g[1], src, 64);
        float t2 = __shfl(d2g[2], src, 64);
        float t3 = __shfl(d2g[3], src, 64);
        const int gsel = (lane >> 3) & 3;
        float d2 = (gsel == 0) ? t0 : (gsel == 1) ? t1 : (gsel == 2) ? t2 : t3;

        // 32-lane softmax (xor offsets 1..16 stay within each half)
        const float s = -d2;
        float m = s;
#pragma unroll
        for (int off = 1; off < 32; off <<= 1)
            m = fmaxf(m, __shfl_xor(m, off, 64));
        const float e = __expf(s - m);
        float ss = e;
#pragma unroll
        for (int off = 1; off < 32; off <<= 1)
            ss += __shfl_xor(ss, off, 64);
        const float logq = (s - m) - __logf(ss);
        const float q = e / ss;

        if (lane < SNL_K) {
            out[1 + (size_t)i * SNL_K + lane] = q;      // coalesced 128B store
            const float pv = psim[(size_t)i * SNL_K + lane];
            loss_acc += pv * (__logf(pv + SNL_EPS) - logq);
        }
    }

    // block reduction of loss partial
#pragma unroll
    for (int off = 1; off < 64; off <<= 1)
        loss_acc += __shfl_xor(loss_acc, off, 64);

    __shared__ float bred[4];
    if (lane == 0) bred[wid] = loss_acc;
    __syncthreads();
    if (tid == 0) part[blockIdx.x] = bred[0] + bred[1] + bred[2] + bred[3];
}

__global__ __launch_bounds__(256) void snl_loss_reduce(const float* __restrict__ part,
                                                       int npart,
                                                       float* __restrict__ out) {
    double acc = 0.0;
    for (int i = threadIdx.x; i < npart; i += 256) acc += (double)part[i];
#pragma unroll
    for (int off = 1; off < 64; off <<= 1)
        acc += __shfl_xor(acc, off, 64);
    __shared__ double sred[4];
    if ((threadIdx.x & 63) == 0) sred[threadIdx.x >> 6] = acc;
    __syncthreads();
    if (threadIdx.x == 0)
        out[0] = (float)((sred[0] + sred[1] + sred[2] + sred[3]) / (double)SNL_N);
}

extern "C" void kernel_launch(void* const* d_in, const int* in_sizes, int n_in,
                              void* d_out, int out_size, void* d_ws, size_t ws_size,
                              hipStream_t stream) {
    const float* emb  = (const float*)d_in[0];
    const float* psim = (const float*)d_in[1];
    const int*   aidx = (const int*)d_in[2];
    float* out  = (float*)d_out;
    float* part = (float*)d_ws;   // SNL_NBLOCKS floats = 25 KB

    snl_main<<<SNL_NBLOCKS, 256, 0, stream>>>(emb, psim, aidx, out, part);
    snl_loss_reduce<<<1, 256, 0, stream>>>(part, SNL_NBLOCKS, out);
}